// Round 14
// baseline (1761.091 us; speedup 1.0000x reference)
//
#include <hip/hip_runtime.h>
#include <cmath>

#define NB 8
#define NPTS 2048
#define NE (NB * NPTS)
#define THREADS 512
#define NBLK 512
#define NPHASE 20
#define NPAIR 2   // packed row-pairs per wave -> 4 rows/wave/half

typedef float v2f __attribute__((ext_vector_type(2)));

#if defined(__has_builtin)
#if __has_builtin(__builtin_amdgcn_exp2f)
#define FAST_EXP2(x) __builtin_amdgcn_exp2f(x)
#else
#define FAST_EXP2(x) exp2f(x)
#endif
#if __has_builtin(__builtin_amdgcn_logf)
#define FAST_LOG2(x) __builtin_amdgcn_logf(x)
#else
#define FAST_LOG2(x) log2f(x)
#endif
#else
#define FAST_EXP2(x) exp2f(x)
#define FAST_LOG2(x) log2f(x)
#endif

// barrier layout in uints; every counter/flag on its own 128-B line
#define C1_OFF(batch, grp) (((batch) * 8 + (grp)) * 32)
#define C2_OFF(batch)      (2048 + (batch) * 32)
#define FL_OFF(batch, grp) (2304 + ((batch) * 8 + (grp)) * 32)
#define GC_OFF             4352
#define BAR_UINTS          4384

// ---- DPP wave64 reductions (VALU pipe only; result valid at lane 63) ----
template<int CTRL>
__device__ __forceinline__ float dpp_f(float v) {
    return __int_as_float(__builtin_amdgcn_update_dpp(
        __float_as_int(v), __float_as_int(v), CTRL, 0xF, 0xF, false));
}
__device__ __forceinline__ float wred_max(float v) {
    v = fmaxf(v, dpp_f<0xB1>(v));
    v = fmaxf(v, dpp_f<0x4E>(v));
    v = fmaxf(v, dpp_f<0x141>(v));
    v = fmaxf(v, dpp_f<0x140>(v));
    v = fmaxf(v, dpp_f<0x142>(v));
    v = fmaxf(v, dpp_f<0x143>(v));
    return v;
}
__device__ __forceinline__ float wred_sum(float v) {
    v += dpp_f<0xB1>(v);
    v += dpp_f<0x4E>(v);
    v += dpp_f<0x141>(v);
    v += dpp_f<0x140>(v);
    v += dpp_f<0x142>(v);
    v += dpp_f<0x143>(v);
    return v;
}

// Persistent annealed Sinkhorn, per-batch sync scope (64 blocks/batch).
// 512 blocks x 512 thr (2 blk/CU vs capacity 4 -> co-residency guaranteed).
// Arrival: 2-level tree, <=8 RMWs per padded line. Release: batch's last
// arriver broadcast-stores 8 padded group flags; spin with s_sleep backoff.
// Final loss: per-batch last arriver bumps gcount; only block 0 spins on it.
__global__ __launch_bounds__(THREADS, 8) void sinkhorn_persistent(
    const float* __restrict__ x, const float* __restrict__ y,
    const float* __restrict__ a, const float* __restrict__ b,
    float* __restrict__ pot0, float* __restrict__ pot1,
    float* __restrict__ partials, unsigned* __restrict__ bar,
    float* __restrict__ out)
{
    __shared__ float4 xy4[NPTS / 2];   // 16 KB {x2k,y2k,x2k+1,y2k+1}
    __shared__ float2 hc2[NPTS / 2];   // 8 KB log2-domain column constant
    __shared__ float bse[NPTS];        // 8 KB log2(w_col)
    __shared__ float pw[8];

    const int blk = blockIdx.x;
    const int side = blk >> 8;          // 256 blocks/side
    const int rblk = blk & 255;
    const int batch = rblk >> 5;        // 32 row-tiles (64 rows) per batch
    const int rowTile = rblk & 31;
    const int grp = side * 4 + (rowTile >> 3);   // 8 groups of 8 blocks per batch

    const float* rowPts = side ? y : x;
    const float* colPts = side ? x : y;
    const float* wcol   = side ? a : b;
    const float* wrow   = side ? b : a;

    const float LOG2E = 1.4426950408889634f;
    const float LN2 = 0.69314718055994531f;

    // ---- one-time staging ----
    const float4* cp4 = ((const float4*)colPts) + (size_t)batch * (NPTS / 2);
    xy4[threadIdx.x]       = cp4[threadIdx.x];
    xy4[threadIdx.x + 512] = cp4[threadIdx.x + 512];
    {
        const float* wl = wcol + (size_t)batch * NPTS;
        #pragma unroll
        for (int k = 0; k < NPTS / THREADS; k++) {
            int j = threadIdx.x + k * THREADS;
            bse[j] = FAST_LOG2(wl[j]);
        }
    }

    const int lane = threadIdx.x & 63;
    const int wv = threadIdx.x >> 6;

    float fown[8], Lown[8];
    #pragma unroll
    for (int r = 0; r < 8; r++) { fown[r] = 0.0f; Lown[r] = 0.0f; }

    // ---- phase loop ----
    double ecur = 4.0, eprev = 4.0;
    for (int ph = 0; ph < NPHASE; ph++) {
        if (ph >= 2 && ph <= 17)      { eprev = ecur; ecur *= 0.64; }
        else if (ph == 18)            { eprev = ecur; ecur = 0.0025; }
        else                          { eprev = ecur; }
        const int init = (ph == 0);
        const int fin  = (ph == NPHASE - 1);
        const float c_old = (init || fin) ? 0.0f : 0.5f;
        const float c_new = (init || fin) ? 1.0f : 0.5f;
        const float eps = (float)ecur;
        const float mscale = (float)(eprev / ecur);
        const float sc = (float)(1.0 / ecur) * LOG2E;

        const float* potR = (ph & 1) ? pot1 : pot0;
        float* potW       = (ph & 1) ? pot0 : pot1;

        // stage hc: hc_j = log2 w_j + (pot_j - |p_j|^2/2) * sc
        {
            float* hcs = (float*)hc2;
            const float2* xys = (const float2*)xy4;
            const float* pp = potR + (1 - side) * NE + batch * NPTS;
            #pragma unroll
            for (int k = 0; k < NPTS / THREADS; k++) {
                int j = threadIdx.x + k * THREADS;
                float2 p = xys[j];
                float n2 = -0.5f * fmaf(p.x, p.x, p.y * p.y);
                float t = init ? n2 : (pp[j] + n2);
                hcs[j] = fmaf(t, sc, bse[j]);
            }
        }
        __syncthreads();

        float part = 0.0f;
        #pragma unroll
        for (int half = 0; half < 2; half++) {
            const int row0 = rowTile * 64 + half * 32 + wv * (2 * NPAIR);
            const int gidx0 = batch * NPTS + row0;
            const float2* rp2 = (const float2*)(rowPts + (size_t)batch * NPTS * 2) + row0;

            v2f rxp[NPAIR], ryp[NPAIR], nmest[NPAIR], sp[NPAIR];
            float pxl[4], pyl[4];
            #pragma unroll
            for (int p = 0; p < NPAIR; p++) {
                float2 p0 = rp2[2 * p];
                float2 p1 = rp2[2 * p + 1];
                pxl[2 * p] = p0.x; pyl[2 * p] = p0.y;
                pxl[2 * p + 1] = p1.x; pyl[2 * p + 1] = p1.y;
                rxp[p] = (v2f){p0.x * sc, p1.x * sc};
                ryp[p] = (v2f){p0.y * sc, p1.y * sc};
                float m0 = init ? 0.0f : Lown[half * 4 + 2 * p] * mscale;
                float m1 = init ? 0.0f : Lown[half * 4 + 2 * p + 1] * mscale;
                nmest[p] = (v2f){-m0, -m1};
                sp[p] = (v2f){0.0f, 0.0f};
            }

            #pragma unroll 4
            for (int it = 0; it < NPTS / 128; it++) {
                float4 v = xy4[(it << 6) + lane];
                float2 h = hc2[(it << 6) + lane];
                #pragma unroll
                for (int p = 0; p < NPAIR; p++) {
                    v2f h0 = (v2f){h.x, h.x} + nmest[p];
                    v2f h1 = (v2f){h.y, h.y} + nmest[p];
                    v2f t0 = __builtin_elementwise_fma(rxp[p], (v2f){v.x, v.x},
                                __builtin_elementwise_fma(ryp[p], (v2f){v.y, v.y}, h0));
                    v2f t1 = __builtin_elementwise_fma(rxp[p], (v2f){v.z, v.z},
                                __builtin_elementwise_fma(ryp[p], (v2f){v.w, v.w}, h1));
                    sp[p] += (v2f){FAST_EXP2(t0.x), FAST_EXP2(t0.y)};
                    sp[p] += (v2f){FAST_EXP2(t1.x), FAST_EXP2(t1.y)};
                }
            }
            float s[4];
            #pragma unroll
            for (int p = 0; p < NPAIR; p++) {
                s[2 * p]     = wred_sum(sp[p].x);
                s[2 * p + 1] = wred_sum(sp[p].y);
            }

            int bad = 0;
            if (lane == 63) {
                #pragma unroll
                for (int r = 0; r < 4; r++)
                    bad |= !(s[r] > 1e-30f && s[r] < 1e34f);
            }
            float mesc[4];
            #pragma unroll
            for (int p = 0; p < NPAIR; p++) {
                mesc[2 * p] = -nmest[p].x; mesc[2 * p + 1] = -nmest[p].y;
            }

            if (__any(bad)) {
                v2f mm[NPAIR];
                #pragma unroll
                for (int p = 0; p < NPAIR; p++) mm[p] = (v2f){-3.4e38f, -3.4e38f};
                #pragma unroll 4
                for (int it = 0; it < NPTS / 128; it++) {
                    float4 v = xy4[(it << 6) + lane];
                    float2 h = hc2[(it << 6) + lane];
                    #pragma unroll
                    for (int p = 0; p < NPAIR; p++) {
                        v2f h0 = (v2f){h.x, h.x} + nmest[p];
                        v2f h1 = (v2f){h.y, h.y} + nmest[p];
                        v2f t0 = __builtin_elementwise_fma(rxp[p], (v2f){v.x, v.x},
                                    __builtin_elementwise_fma(ryp[p], (v2f){v.y, v.y}, h0));
                        v2f t1 = __builtin_elementwise_fma(rxp[p], (v2f){v.z, v.z},
                                    __builtin_elementwise_fma(ryp[p], (v2f){v.w, v.w}, h1));
                        mm[p] = __builtin_elementwise_max(mm[p],
                                    __builtin_elementwise_max(t0, t1));
                    }
                }
                float mmsc[4];
                #pragma unroll
                for (int p = 0; p < NPAIR; p++) {
                    mmsc[2 * p] = mm[p].x; mmsc[2 * p + 1] = mm[p].y;
                }
                #pragma unroll
                for (int r = 0; r < 4; r++) {
                    mmsc[r] = wred_max(mmsc[r]);
                    mmsc[r] = __shfl(mmsc[r], 63);
                }
                v2f mmb[NPAIR];
                #pragma unroll
                for (int p = 0; p < NPAIR; p++) {
                    mmb[p] = (v2f){mmsc[2 * p], mmsc[2 * p + 1]};
                    sp[p] = (v2f){0.0f, 0.0f};
                }
                #pragma unroll 4
                for (int it = 0; it < NPTS / 128; it++) {
                    float4 v = xy4[(it << 6) + lane];
                    float2 h = hc2[(it << 6) + lane];
                    #pragma unroll
                    for (int p = 0; p < NPAIR; p++) {
                        v2f h0 = (v2f){h.x, h.x} + nmest[p] - mmb[p];
                        v2f h1 = (v2f){h.y, h.y} + nmest[p] - mmb[p];
                        v2f t0 = __builtin_elementwise_fma(rxp[p], (v2f){v.x, v.x},
                                    __builtin_elementwise_fma(ryp[p], (v2f){v.y, v.y}, h0));
                        v2f t1 = __builtin_elementwise_fma(rxp[p], (v2f){v.z, v.z},
                                    __builtin_elementwise_fma(ryp[p], (v2f){v.w, v.w}, h1));
                        sp[p] += (v2f){FAST_EXP2(t0.x), FAST_EXP2(t0.y)};
                        sp[p] += (v2f){FAST_EXP2(t1.x), FAST_EXP2(t1.y)};
                    }
                }
                #pragma unroll
                for (int p = 0; p < NPAIR; p++) {
                    s[2 * p]     = wred_sum(sp[p].x);
                    s[2 * p + 1] = wred_sum(sp[p].y);
                    mesc[2 * p] += mmb[p].x;
                    mesc[2 * p + 1] += mmb[p].y;
                }
            }

            // epilogue (uniform via lane-63 broadcast)
            #pragma unroll
            for (int r = 0; r < 4; r++) {
                float sb = __shfl(s[r], 63);
                float L = mesc[r] + FAST_LOG2(sb);
                Lown[half * 4 + r] = L;
                float hr = -0.5f * sc * fmaf(pxl[r], pxl[r], pyl[r] * pyl[r]);
                float sm = -eps * LN2 * (hr + L);
                fown[half * 4 + r] = c_old * fown[half * 4 + r] + c_new * sm;
            }
            if (lane == 63) {
                #pragma unroll
                for (int r = 0; r < 4; r++)
                    potW[side * NE + gidx0 + r] = fown[half * 4 + r];
                if (fin) {
                    #pragma unroll
                    for (int r = 0; r < 4; r++)
                        part += wrow[gidx0 + r] * fown[half * 4 + r];
                }
            }
        }

        if (fin) {
            if (lane == 63) pw[wv] = part;
            __syncthreads();
            if (threadIdx.x == 0) {
                float t = 0.0f;
                #pragma unroll
                for (int i = 0; i < 8; i++) t += pw[i];
                partials[blk] = t;
            }
        }

        // ---- per-batch barrier (64 blocks; padded tree; broadcast release)
        __syncthreads();
        if (threadIdx.x == 0) {
            const unsigned target = (unsigned)(ph + 1);
            __threadfence();
            unsigned t1 = __hip_atomic_fetch_add(bar + C1_OFF(batch, grp), 1u,
                              __ATOMIC_ACQ_REL, __HIP_MEMORY_SCOPE_AGENT);
            if ((t1 & 7u) == 7u) {
                unsigned t2 = __hip_atomic_fetch_add(bar + C2_OFF(batch), 1u,
                                  __ATOMIC_ACQ_REL, __HIP_MEMORY_SCOPE_AGENT);
                if ((t2 & 7u) == 7u) {
                    #pragma unroll
                    for (int i = 0; i < 8; i++)
                        __hip_atomic_store(bar + FL_OFF(batch, i), target,
                                           __ATOMIC_RELEASE, __HIP_MEMORY_SCOPE_AGENT);
                    if (fin)
                        __hip_atomic_fetch_add(bar + GC_OFF, 1u,
                                               __ATOMIC_ACQ_REL, __HIP_MEMORY_SCOPE_AGENT);
                }
            }
            if (!fin) {
                long cap = 500000000;
                while (__hip_atomic_load(bar + FL_OFF(batch, grp), __ATOMIC_ACQUIRE,
                                         __HIP_MEMORY_SCOPE_AGENT) < target && --cap)
                    __builtin_amdgcn_s_sleep(8);
            }
        }
        __syncthreads();
    }

    // block 0: wait for all 8 batches' last arrivers, then reduce partials
    if (blk == 0) {
        if (threadIdx.x == 0) {
            long cap = 500000000;
            while (__hip_atomic_load(bar + GC_OFF, __ATOMIC_ACQUIRE,
                                     __HIP_MEMORY_SCOPE_AGENT) < 8u && --cap)
                __builtin_amdgcn_s_sleep(8);
        }
        __syncthreads();
        float v = partials[threadIdx.x];
        v = wred_sum(v);
        if (lane == 63) pw[wv] = v;
        __syncthreads();
        if (threadIdx.x == 0) {
            float t = 0.0f;
            #pragma unroll
            for (int i = 0; i < 8; i++) t += pw[i];
            out[0] = t * (1.0f / NB);
        }
    }
}

extern "C" void kernel_launch(void* const* d_in, const int* in_sizes, int n_in,
                              void* d_out, int out_size, void* d_ws, size_t ws_size,
                              hipStream_t stream)
{
    const float* a = (const float*)d_in[0];
    const float* x = (const float*)d_in[1];
    const float* b = (const float*)d_in[2];
    const float* y = (const float*)d_in[3];
    float* out = (float*)d_out;

    float* ws = (float*)d_ws;
    float* pot0 = ws;                   // [2][NB][NPTS]
    float* pot1 = ws + 2 * NE;          // [2][NB][NPTS]
    float* partials = ws + 4 * NE;      // 512 floats
    unsigned* bar = (unsigned*)(ws + 4 * NE + 1024);

    (void)hipMemsetAsync(bar, 0, BAR_UINTS * sizeof(unsigned), stream);
    sinkhorn_persistent<<<NBLK, THREADS, 0, stream>>>(
        x, y, a, b, pot0, pot1, partials, bar, out);
}

// Round 15
// 272.981 us; speedup vs baseline: 6.4513x; 6.4513x over previous
//
#include <hip/hip_runtime.h>
#include <cmath>

#define NB 8
#define NPTS 2048
#define NE (NB * NPTS)
#define THREADS 512
#define NPAIR 2   // packed row-pairs per wave -> 4 rows/wave, 32 rows/block, 1024 blocks

typedef float v2f __attribute__((ext_vector_type(2)));

#if defined(__has_builtin)
#if __has_builtin(__builtin_amdgcn_exp2f)
#define FAST_EXP2(x) __builtin_amdgcn_exp2f(x)
#else
#define FAST_EXP2(x) exp2f(x)
#endif
#if __has_builtin(__builtin_amdgcn_logf)
#define FAST_LOG2(x) __builtin_amdgcn_logf(x)
#else
#define FAST_LOG2(x) log2f(x)
#endif
#else
#define FAST_EXP2(x) exp2f(x)
#define FAST_LOG2(x) log2f(x)
#endif

// ---- DPP wave64 reductions (VALU pipe only; result valid at lane 63) ----
template<int CTRL>
__device__ __forceinline__ float dpp_f(float v) {
    return __int_as_float(__builtin_amdgcn_update_dpp(
        __float_as_int(v), __float_as_int(v), CTRL, 0xF, 0xF, false));
}
__device__ __forceinline__ float wred_max(float v) {
    v = fmaxf(v, dpp_f<0xB1>(v));
    v = fmaxf(v, dpp_f<0x4E>(v));
    v = fmaxf(v, dpp_f<0x141>(v));
    v = fmaxf(v, dpp_f<0x140>(v));
    v = fmaxf(v, dpp_f<0x142>(v));
    v = fmaxf(v, dpp_f<0x143>(v));
    return v;
}
__device__ __forceinline__ float wred_sum(float v) {
    v += dpp_f<0xB1>(v);
    v += dpp_f<0x4E>(v);
    v += dpp_f<0x141>(v);
    v += dpp_f<0x140>(v);
    v += dpp_f<0x142>(v);
    v += dpp_f<0x143>(v);
    return v;
}

// One Sinkhorn "phase" (R11 structure + q-folding + vectorized staging).
// q = pot + n2 (n2 = -|p|^2/2) is the ping-pong state: steady staging is
// hc4 = fma(q4, sc, bse4) from two float4 streams. Stabilizer m_est =
// prev LSE * eps-ratio, band-validated (s in (1e-30,1e34)); exact
// wave-local 2-pass redo otherwise. finalPhase fuses the loss partials.
__global__ __launch_bounds__(THREADS, 8) void sinkhorn_phase(
    const float* __restrict__ x, const float* __restrict__ y,
    const float* __restrict__ a, const float* __restrict__ b,
    const float* __restrict__ qR, float* __restrict__ qW,
    float* __restrict__ Ls,          // [2][NB][NPTS] log2-domain LSE store
    float* __restrict__ colBase,     // [2][NB][NPTS] log2(w_col), init-written
    float* __restrict__ partials,    // [1024] final-phase partial sums
    float eps, float inv_eps, float c_old, float c_new,
    float mscale, int initPhase, int finalPhase)
{
    __shared__ float4 xy4[NPTS / 2];   // 16 KB: {x_2k, y_2k, x_2k+1, y_2k+1}
    __shared__ float2 hc2[NPTS / 2];   // 8 KB: {hc_2k, hc_2k+1}
    __shared__ float pw[8];

    const int blk = blockIdx.x;
    const int side = blk >> 9;          // 512 blocks/side
    const int rblk = blk & 511;
    const int batch = rblk >> 6;        // 64 row-tiles (32 rows) per batch
    const int rowTile = rblk & 63;

    const float* rowPts = side ? y : x;
    const float* colPts = side ? x : y;
    const float* wcol   = side ? a : b;
    const float* wrow   = side ? b : a;

    const float LOG2E = 1.4426950408889634f;
    const float LN2 = 0.69314718055994531f;
    const float sc = inv_eps * LOG2E;
    const int colOff = side * NE + batch * NPTS;   // opposite-side cols use (1-side)

    // Stage xy: pure float4 copy (coalesced, no math).
    const float4* cp4 = ((const float4*)colPts) + (size_t)batch * (NPTS / 2);
    xy4[threadIdx.x]       = cp4[threadIdx.x];
    xy4[threadIdx.x + 512] = cp4[threadIdx.x + 512];

    // Stage hc.
    {
        float* hcs = (float*)hc2;
        if (initPhase) {
            const float2* cp2 = (const float2*)(colPts + (size_t)batch * NPTS * 2);
            const float* wl = wcol + (size_t)batch * NPTS;
            const int cOpp = (1 - side) * NE + batch * NPTS;
            #pragma unroll
            for (int k = 0; k < NPTS / THREADS; k++) {
                int j = threadIdx.x + k * THREADS;
                float2 p = cp2[j];
                float n2 = -0.5f * fmaf(p.x, p.x, p.y * p.y);
                float bsev = FAST_LOG2(wl[j]);
                hcs[j] = fmaf(n2, sc, bsev);
                if (rowTile == 0) colBase[cOpp + j] = bsev;
            }
        } else {
            const float4* qq = (const float4*)(qR + (1 - side) * NE + batch * NPTS);
            const float4* bb = (const float4*)(colBase + (1 - side) * NE + batch * NPTS);
            float4 qv = qq[threadIdx.x];
            float4 bv = bb[threadIdx.x];
            float4 h;
            h.x = fmaf(qv.x, sc, bv.x);
            h.y = fmaf(qv.y, sc, bv.y);
            h.z = fmaf(qv.z, sc, bv.z);
            h.w = fmaf(qv.w, sc, bv.w);
            ((float4*)hcs)[threadIdx.x] = h;
        }
    }
    __syncthreads();

    const int lane = threadIdx.x & 63;
    const int wv = threadIdx.x >> 6;        // 8 waves/block
    const int row0 = rowTile * 32 + wv * (2 * NPAIR);
    const int gidx0 = batch * NPTS + row0;
    const float2* rp2 = (const float2*)(rowPts + (size_t)batch * NPTS * 2) + row0;
    const float* Lp = Ls + side * NE + gidx0;

    v2f rxp[NPAIR], ryp[NPAIR], nmest[NPAIR], sp[NPAIR];
    #pragma unroll
    for (int p = 0; p < NPAIR; p++) {
        float2 p0 = rp2[2 * p];
        float2 p1 = rp2[2 * p + 1];
        rxp[p] = (v2f){p0.x * sc, p1.x * sc};
        ryp[p] = (v2f){p0.y * sc, p1.y * sc};
        float m0 = initPhase ? 0.0f : Lp[2 * p] * mscale;
        float m1 = initPhase ? 0.0f : Lp[2 * p + 1] * mscale;
        nmest[p] = (v2f){-m0, -m1};
        sp[p] = (v2f){0.0f, 0.0f};
    }

    // Fused pass: 16 iters; per iter 2 cols x 4 rows = 8 elements.
    #pragma unroll 4
    for (int it = 0; it < NPTS / 128; it++) {
        float4 v = xy4[(it << 6) + lane];
        float2 h = hc2[(it << 6) + lane];
        #pragma unroll
        for (int p = 0; p < NPAIR; p++) {
            v2f h0 = (v2f){h.x, h.x} + nmest[p];
            v2f h1 = (v2f){h.y, h.y} + nmest[p];
            v2f t0 = __builtin_elementwise_fma(rxp[p], (v2f){v.x, v.x},
                        __builtin_elementwise_fma(ryp[p], (v2f){v.y, v.y}, h0));
            v2f t1 = __builtin_elementwise_fma(rxp[p], (v2f){v.z, v.z},
                        __builtin_elementwise_fma(ryp[p], (v2f){v.w, v.w}, h1));
            sp[p] += (v2f){FAST_EXP2(t0.x), FAST_EXP2(t0.y)};
            sp[p] += (v2f){FAST_EXP2(t1.x), FAST_EXP2(t1.y)};
        }
    }
    float s[4];
    #pragma unroll
    for (int p = 0; p < NPAIR; p++) {
        s[2 * p]     = wred_sum(sp[p].x);
        s[2 * p + 1] = wred_sum(sp[p].y);
    }

    int bad = 0;
    if (lane == 63) {
        #pragma unroll
        for (int r = 0; r < 4; r++)
            bad |= !(s[r] > 1e-30f && s[r] < 1e34f);
    }
    float mesc[4];
    #pragma unroll
    for (int p = 0; p < NPAIR; p++) {
        mesc[2 * p] = -nmest[p].x; mesc[2 * p + 1] = -nmest[p].y;
    }

    if (__any(bad)) {
        // Exact 2-pass redo (wave-local; no barrier needed).
        v2f mm[NPAIR];
        #pragma unroll
        for (int p = 0; p < NPAIR; p++) mm[p] = (v2f){-3.4e38f, -3.4e38f};
        #pragma unroll 4
        for (int it = 0; it < NPTS / 128; it++) {
            float4 v = xy4[(it << 6) + lane];
            float2 h = hc2[(it << 6) + lane];
            #pragma unroll
            for (int p = 0; p < NPAIR; p++) {
                v2f h0 = (v2f){h.x, h.x} + nmest[p];
                v2f h1 = (v2f){h.y, h.y} + nmest[p];
                v2f t0 = __builtin_elementwise_fma(rxp[p], (v2f){v.x, v.x},
                            __builtin_elementwise_fma(ryp[p], (v2f){v.y, v.y}, h0));
                v2f t1 = __builtin_elementwise_fma(rxp[p], (v2f){v.z, v.z},
                            __builtin_elementwise_fma(ryp[p], (v2f){v.w, v.w}, h1));
                mm[p] = __builtin_elementwise_max(mm[p],
                            __builtin_elementwise_max(t0, t1));
            }
        }
        float mmsc[4];
        #pragma unroll
        for (int p = 0; p < NPAIR; p++) {
            mmsc[2 * p] = mm[p].x; mmsc[2 * p + 1] = mm[p].y;
        }
        #pragma unroll
        for (int r = 0; r < 4; r++) {
            mmsc[r] = wred_max(mmsc[r]);
            mmsc[r] = __shfl(mmsc[r], 63);
        }
        v2f mmb[NPAIR];
        #pragma unroll
        for (int p = 0; p < NPAIR; p++) {
            mmb[p] = (v2f){mmsc[2 * p], mmsc[2 * p + 1]};
            sp[p] = (v2f){0.0f, 0.0f};
        }
        #pragma unroll 4
        for (int it = 0; it < NPTS / 128; it++) {
            float4 v = xy4[(it << 6) + lane];
            float2 h = hc2[(it << 6) + lane];
            #pragma unroll
            for (int p = 0; p < NPAIR; p++) {
                v2f h0 = (v2f){h.x, h.x} + nmest[p] - mmb[p];
                v2f h1 = (v2f){h.y, h.y} + nmest[p] - mmb[p];
                v2f t0 = __builtin_elementwise_fma(rxp[p], (v2f){v.x, v.x},
                            __builtin_elementwise_fma(ryp[p], (v2f){v.y, v.y}, h0));
                v2f t1 = __builtin_elementwise_fma(rxp[p], (v2f){v.z, v.z},
                            __builtin_elementwise_fma(ryp[p], (v2f){v.w, v.w}, h1));
                sp[p] += (v2f){FAST_EXP2(t0.x), FAST_EXP2(t0.y)};
                sp[p] += (v2f){FAST_EXP2(t1.x), FAST_EXP2(t1.y)};
            }
        }
        #pragma unroll
        for (int p = 0; p < NPAIR; p++) {
            s[2 * p]     = wred_sum(sp[p].x);
            s[2 * p + 1] = wred_sum(sp[p].y);
            mesc[2 * p] += mmb[p].x;
            mesc[2 * p + 1] += mmb[p].y;
        }
    }

    if (lane == 63) {
        float4 qout, Lout;
        float part = 0.0f;
        float4 qprev = {0.0f, 0.0f, 0.0f, 0.0f};
        if (!initPhase && c_old != 0.0f)
            qprev = *(const float4*)&qR[side * NE + gidx0];
        const float* qpv = (const float*)&qprev;
        float* qo = (float*)&qout;
        float* Lo = (float*)&Lout;
        #pragma unroll
        for (int r = 0; r < 4; r++) {
            float2 p = rp2[r];
            float n2o = -0.5f * fmaf(p.x, p.x, p.y * p.y);
            float L = mesc[r] + FAST_LOG2(s[r]);
            float sm = -eps * LN2 * fmaf(n2o, sc, L);     // -eps*ln2*(hr + L)
            float fprev = qpv[r] - n2o;
            float fnew = c_old * fprev + c_new * sm;
            qo[r] = fnew + n2o;
            Lo[r] = L;
            if (finalPhase) part += wrow[gidx0 + r] * fnew;
        }
        *(float4*)&qW[side * NE + gidx0] = qout;
        *(float4*)&Ls[side * NE + gidx0] = Lout;
        if (finalPhase) pw[wv] = part;
    }
    if (finalPhase) {
        __syncthreads();
        if (threadIdx.x == 0) {
            float t = 0.0f;
            #pragma unroll
            for (int i = 0; i < 8; i++) t += pw[i];
            partials[blk] = t;
        }
    }
}

__global__ __launch_bounds__(512) void final_reduce(
    const float* __restrict__ partials, float* __restrict__ out)
{
    float v = partials[threadIdx.x] + partials[threadIdx.x + 512];
    v += __shfl_xor(v, 32);
    v += __shfl_xor(v, 16);
    v += __shfl_xor(v, 8);
    v += __shfl_xor(v, 4);
    v += __shfl_xor(v, 2);
    v += __shfl_xor(v, 1);
    __shared__ float ws8[8];
    if ((threadIdx.x & 63) == 0) ws8[threadIdx.x >> 6] = v;
    __syncthreads();
    if (threadIdx.x == 0) {
        float t = 0.0f;
        #pragma unroll
        for (int i = 0; i < 8; i++) t += ws8[i];
        out[0] = t * (1.0f / NB);
    }
}

extern "C" void kernel_launch(void* const* d_in, const int* in_sizes, int n_in,
                              void* d_out, int out_size, void* d_ws, size_t ws_size,
                              hipStream_t stream)
{
    const float* a = (const float*)d_in[0];
    const float* x = (const float*)d_in[1];
    const float* b = (const float*)d_in[2];
    const float* y = (const float*)d_in[3];
    float* out = (float*)d_out;

    float* ws = (float*)d_ws;
    float* q0 = ws;                 // [2][NB][NPTS]  (q = pot + n2)
    float* q1 = ws + 2 * NE;
    float* Ls = ws + 4 * NE;        // [2][NB][NPTS]
    float* colBase = ws + 6 * NE;   // [2][NB][NPTS]
    float* partials = ws + 8 * NE;  // 1024 floats

    // eps annealing schedule (host-side, as in reference)
    double eps_list[32];
    int ne = 0;
    const double eps_final = 0.05 * 0.05;   // blur^p
    double eps = 2.0 * 2.0;                  // diameter^p
    while (eps > eps_final) { eps_list[ne++] = eps; eps *= 0.64; }  // scaling^p
    eps_list[ne++] = eps_final;              // ne == 18

    const float* qp = q0;
    float* qn = q1;

    auto phase = [&](double e, double e_prev, float c_old, float c_new,
                     int init, int fin) {
        sinkhorn_phase<<<1024, THREADS, 0, stream>>>(
            x, y, a, b, qp, qn, Ls, colBase, partials,
            (float)e, (float)(1.0 / e), c_old, c_new,
            (float)(e_prev / e), init, fin);
    };
    auto swapbuf = [&]() {
        const float* t = qp; qp = qn; qn = (float*)t;
    };

    // init at eps0 (mest=0 in-band; band check still guards correctness)
    phase(eps_list[0], eps_list[0], 0.0f, 1.0f, 1, 0);
    swapbuf();
    // annealed damped iterations
    double e_prev = eps_list[0];
    for (int k = 0; k < ne; k++) {
        phase(eps_list[k], e_prev, 0.5f, 0.5f, 0, 0);
        e_prev = eps_list[k];
        swapbuf();
    }
    // final extrapolation at eps_final (no damping) + fused partial loss
    phase(eps_list[ne - 1], e_prev, 0.0f, 1.0f, 0, 1);

    final_reduce<<<1, 512, 0, stream>>>(partials, out);
}

// Round 16
// 263.190 us; speedup vs baseline: 6.6913x; 1.0372x over previous
//
#include <hip/hip_runtime.h>
#include <cmath>

#define NB 8
#define NPTS 2048
#define NE (NB * NPTS)
#define THREADS 512
#define NPAIR 2   // packed row-pairs per wave -> 4 rows/wave, 32 rows/block, 1024 blocks

typedef float v2f __attribute__((ext_vector_type(2)));

#if defined(__has_builtin)
#if __has_builtin(__builtin_amdgcn_exp2f)
#define FAST_EXP2(x) __builtin_amdgcn_exp2f(x)
#else
#define FAST_EXP2(x) exp2f(x)
#endif
#if __has_builtin(__builtin_amdgcn_logf)
#define FAST_LOG2(x) __builtin_amdgcn_logf(x)
#else
#define FAST_LOG2(x) log2f(x)
#endif
#else
#define FAST_EXP2(x) exp2f(x)
#define FAST_LOG2(x) log2f(x)
#endif

// ---- DPP wave64 reductions (VALU pipe only; result valid at lane 63) ----
template<int CTRL>
__device__ __forceinline__ float dpp_f(float v) {
    return __int_as_float(__builtin_amdgcn_update_dpp(
        __float_as_int(v), __float_as_int(v), CTRL, 0xF, 0xF, false));
}
__device__ __forceinline__ float wred_max(float v) {
    v = fmaxf(v, dpp_f<0xB1>(v));
    v = fmaxf(v, dpp_f<0x4E>(v));
    v = fmaxf(v, dpp_f<0x141>(v));
    v = fmaxf(v, dpp_f<0x140>(v));
    v = fmaxf(v, dpp_f<0x142>(v));
    v = fmaxf(v, dpp_f<0x143>(v));
    return v;
}
__device__ __forceinline__ float wred_sum(float v) {
    v += dpp_f<0xB1>(v);
    v += dpp_f<0x4E>(v);
    v += dpp_f<0x141>(v);
    v += dpp_f<0x140>(v);
    v += dpp_f<0x142>(v);
    v += dpp_f<0x143>(v);
    return v;
}

// One Sinkhorn "phase" (R15 structure + XCD-aware block remap).
// Block remap: batch = hw & 7 -> all 128 blocks of a batch land on one XCD
// (round-robin dispatch), so the ping-pong q/Ls/colBase traffic stays in
// that XCD's L2 across phases. q = pot + n2 (n2 = -|p|^2/2) is the state:
// steady staging is hc4 = fma(q4, sc, bse4) from two float4 streams.
// Stabilizer m_est = prev LSE * eps-ratio, band-validated (s in
// (1e-30,1e34)); exact wave-local 2-pass redo otherwise. finalPhase fuses
// the loss partials.
__global__ __launch_bounds__(THREADS, 8) void sinkhorn_phase(
    const float* __restrict__ x, const float* __restrict__ y,
    const float* __restrict__ a, const float* __restrict__ b,
    const float* __restrict__ qR, float* __restrict__ qW,
    float* __restrict__ Ls,          // [2][NB][NPTS] log2-domain LSE store
    float* __restrict__ colBase,     // [2][NB][NPTS] log2(w_col), init-written
    float* __restrict__ partials,    // [1024] final-phase partial sums
    float eps, float inv_eps, float c_old, float c_new,
    float mscale, int initPhase, int finalPhase)
{
    __shared__ float4 xy4[NPTS / 2];   // 16 KB: {x_2k, y_2k, x_2k+1, y_2k+1}
    __shared__ float2 hc2[NPTS / 2];   // 8 KB: {hc_2k, hc_2k+1}
    __shared__ float pw[8];

    // XCD-aware remap (bijective on [0,1024)): batch = hw & 7 -> XCD b.
    const int hw = blockIdx.x;
    const int batch = hw & 7;
    const int pos = hw >> 3;            // 0..127
    const int side = pos >> 6;          // 64 row-tiles per side per batch
    const int rowTile = pos & 63;

    const float* rowPts = side ? y : x;
    const float* colPts = side ? x : y;
    const float* wcol   = side ? a : b;
    const float* wrow   = side ? b : a;

    const float LOG2E = 1.4426950408889634f;
    const float LN2 = 0.69314718055994531f;
    const float sc = inv_eps * LOG2E;

    // Stage xy: pure float4 copy (coalesced, no math).
    const float4* cp4 = ((const float4*)colPts) + (size_t)batch * (NPTS / 2);
    xy4[threadIdx.x]       = cp4[threadIdx.x];
    xy4[threadIdx.x + 512] = cp4[threadIdx.x + 512];

    // Stage hc.
    {
        float* hcs = (float*)hc2;
        if (initPhase) {
            const float2* cp2 = (const float2*)(colPts + (size_t)batch * NPTS * 2);
            const float* wl = wcol + (size_t)batch * NPTS;
            const int cOpp = (1 - side) * NE + batch * NPTS;
            #pragma unroll
            for (int k = 0; k < NPTS / THREADS; k++) {
                int j = threadIdx.x + k * THREADS;
                float2 p = cp2[j];
                float n2 = -0.5f * fmaf(p.x, p.x, p.y * p.y);
                float bsev = FAST_LOG2(wl[j]);
                hcs[j] = fmaf(n2, sc, bsev);
                if (rowTile == 0) colBase[cOpp + j] = bsev;
            }
        } else {
            const float4* qq = (const float4*)(qR + (1 - side) * NE + batch * NPTS);
            const float4* bb = (const float4*)(colBase + (1 - side) * NE + batch * NPTS);
            float4 qv = qq[threadIdx.x];
            float4 bv = bb[threadIdx.x];
            float4 h;
            h.x = fmaf(qv.x, sc, bv.x);
            h.y = fmaf(qv.y, sc, bv.y);
            h.z = fmaf(qv.z, sc, bv.z);
            h.w = fmaf(qv.w, sc, bv.w);
            ((float4*)hcs)[threadIdx.x] = h;
        }
    }
    __syncthreads();

    const int lane = threadIdx.x & 63;
    const int wv = threadIdx.x >> 6;        // 8 waves/block
    const int row0 = rowTile * 32 + wv * (2 * NPAIR);
    const int gidx0 = batch * NPTS + row0;
    const float2* rp2 = (const float2*)(rowPts + (size_t)batch * NPTS * 2) + row0;
    const float* Lp = Ls + side * NE + gidx0;

    v2f rxp[NPAIR], ryp[NPAIR], nmest[NPAIR], sp[NPAIR];
    #pragma unroll
    for (int p = 0; p < NPAIR; p++) {
        float2 p0 = rp2[2 * p];
        float2 p1 = rp2[2 * p + 1];
        rxp[p] = (v2f){p0.x * sc, p1.x * sc};
        ryp[p] = (v2f){p0.y * sc, p1.y * sc};
        float m0 = initPhase ? 0.0f : Lp[2 * p] * mscale;
        float m1 = initPhase ? 0.0f : Lp[2 * p + 1] * mscale;
        nmest[p] = (v2f){-m0, -m1};
        sp[p] = (v2f){0.0f, 0.0f};
    }

    // Fused pass: 16 iters; per iter 2 cols x 4 rows = 8 elements.
    #pragma unroll 8
    for (int it = 0; it < NPTS / 128; it++) {
        float4 v = xy4[(it << 6) + lane];
        float2 h = hc2[(it << 6) + lane];
        #pragma unroll
        for (int p = 0; p < NPAIR; p++) {
            v2f h0 = (v2f){h.x, h.x} + nmest[p];
            v2f h1 = (v2f){h.y, h.y} + nmest[p];
            v2f t0 = __builtin_elementwise_fma(rxp[p], (v2f){v.x, v.x},
                        __builtin_elementwise_fma(ryp[p], (v2f){v.y, v.y}, h0));
            v2f t1 = __builtin_elementwise_fma(rxp[p], (v2f){v.z, v.z},
                        __builtin_elementwise_fma(ryp[p], (v2f){v.w, v.w}, h1));
            sp[p] += (v2f){FAST_EXP2(t0.x), FAST_EXP2(t0.y)};
            sp[p] += (v2f){FAST_EXP2(t1.x), FAST_EXP2(t1.y)};
        }
    }
    float s[4];
    #pragma unroll
    for (int p = 0; p < NPAIR; p++) {
        s[2 * p]     = wred_sum(sp[p].x);
        s[2 * p + 1] = wred_sum(sp[p].y);
    }

    int bad = 0;
    if (lane == 63) {
        #pragma unroll
        for (int r = 0; r < 4; r++)
            bad |= !(s[r] > 1e-30f && s[r] < 1e34f);
    }
    float mesc[4];
    #pragma unroll
    for (int p = 0; p < NPAIR; p++) {
        mesc[2 * p] = -nmest[p].x; mesc[2 * p + 1] = -nmest[p].y;
    }

    if (__any(bad)) {
        // Exact 2-pass redo (wave-local; no barrier needed).
        v2f mm[NPAIR];
        #pragma unroll
        for (int p = 0; p < NPAIR; p++) mm[p] = (v2f){-3.4e38f, -3.4e38f};
        #pragma unroll 4
        for (int it = 0; it < NPTS / 128; it++) {
            float4 v = xy4[(it << 6) + lane];
            float2 h = hc2[(it << 6) + lane];
            #pragma unroll
            for (int p = 0; p < NPAIR; p++) {
                v2f h0 = (v2f){h.x, h.x} + nmest[p];
                v2f h1 = (v2f){h.y, h.y} + nmest[p];
                v2f t0 = __builtin_elementwise_fma(rxp[p], (v2f){v.x, v.x},
                            __builtin_elementwise_fma(ryp[p], (v2f){v.y, v.y}, h0));
                v2f t1 = __builtin_elementwise_fma(rxp[p], (v2f){v.z, v.z},
                            __builtin_elementwise_fma(ryp[p], (v2f){v.w, v.w}, h1));
                mm[p] = __builtin_elementwise_max(mm[p],
                            __builtin_elementwise_max(t0, t1));
            }
        }
        float mmsc[4];
        #pragma unroll
        for (int p = 0; p < NPAIR; p++) {
            mmsc[2 * p] = mm[p].x; mmsc[2 * p + 1] = mm[p].y;
        }
        #pragma unroll
        for (int r = 0; r < 4; r++) {
            mmsc[r] = wred_max(mmsc[r]);
            mmsc[r] = __shfl(mmsc[r], 63);
        }
        v2f mmb[NPAIR];
        #pragma unroll
        for (int p = 0; p < NPAIR; p++) {
            mmb[p] = (v2f){mmsc[2 * p], mmsc[2 * p + 1]};
            sp[p] = (v2f){0.0f, 0.0f};
        }
        #pragma unroll 4
        for (int it = 0; it < NPTS / 128; it++) {
            float4 v = xy4[(it << 6) + lane];
            float2 h = hc2[(it << 6) + lane];
            #pragma unroll
            for (int p = 0; p < NPAIR; p++) {
                v2f h0 = (v2f){h.x, h.x} + nmest[p] - mmb[p];
                v2f h1 = (v2f){h.y, h.y} + nmest[p] - mmb[p];
                v2f t0 = __builtin_elementwise_fma(rxp[p], (v2f){v.x, v.x},
                            __builtin_elementwise_fma(ryp[p], (v2f){v.y, v.y}, h0));
                v2f t1 = __builtin_elementwise_fma(rxp[p], (v2f){v.z, v.z},
                            __builtin_elementwise_fma(ryp[p], (v2f){v.w, v.w}, h1));
                sp[p] += (v2f){FAST_EXP2(t0.x), FAST_EXP2(t0.y)};
                sp[p] += (v2f){FAST_EXP2(t1.x), FAST_EXP2(t1.y)};
            }
        }
        #pragma unroll
        for (int p = 0; p < NPAIR; p++) {
            s[2 * p]     = wred_sum(sp[p].x);
            s[2 * p + 1] = wred_sum(sp[p].y);
            mesc[2 * p] += mmb[p].x;
            mesc[2 * p + 1] += mmb[p].y;
        }
    }

    if (lane == 63) {
        float4 qout, Lout;
        float part = 0.0f;
        float4 qprev = {0.0f, 0.0f, 0.0f, 0.0f};
        if (!initPhase && c_old != 0.0f)
            qprev = *(const float4*)&qR[side * NE + gidx0];
        const float* qpv = (const float*)&qprev;
        float* qo = (float*)&qout;
        float* Lo = (float*)&Lout;
        #pragma unroll
        for (int r = 0; r < 4; r++) {
            float2 p = rp2[r];
            float n2o = -0.5f * fmaf(p.x, p.x, p.y * p.y);
            float L = mesc[r] + FAST_LOG2(s[r]);
            float sm = -eps * LN2 * fmaf(n2o, sc, L);     // -eps*ln2*(hr + L)
            float fprev = qpv[r] - n2o;
            float fnew = c_old * fprev + c_new * sm;
            qo[r] = fnew + n2o;
            Lo[r] = L;
            if (finalPhase) part += wrow[gidx0 + r] * fnew;
        }
        *(float4*)&qW[side * NE + gidx0] = qout;
        *(float4*)&Ls[side * NE + gidx0] = Lout;
        if (finalPhase) pw[wv] = part;
    }
    if (finalPhase) {
        __syncthreads();
        if (threadIdx.x == 0) {
            float t = 0.0f;
            #pragma unroll
            for (int i = 0; i < 8; i++) t += pw[i];
            partials[hw] = t;
        }
    }
}

__global__ __launch_bounds__(512) void final_reduce(
    const float* __restrict__ partials, float* __restrict__ out)
{
    float v = partials[threadIdx.x] + partials[threadIdx.x + 512];
    v += __shfl_xor(v, 32);
    v += __shfl_xor(v, 16);
    v += __shfl_xor(v, 8);
    v += __shfl_xor(v, 4);
    v += __shfl_xor(v, 2);
    v += __shfl_xor(v, 1);
    __shared__ float ws8[8];
    if ((threadIdx.x & 63) == 0) ws8[threadIdx.x >> 6] = v;
    __syncthreads();
    if (threadIdx.x == 0) {
        float t = 0.0f;
        #pragma unroll
        for (int i = 0; i < 8; i++) t += ws8[i];
        out[0] = t * (1.0f / NB);
    }
}

extern "C" void kernel_launch(void* const* d_in, const int* in_sizes, int n_in,
                              void* d_out, int out_size, void* d_ws, size_t ws_size,
                              hipStream_t stream)
{
    const float* a = (const float*)d_in[0];
    const float* x = (const float*)d_in[1];
    const float* b = (const float*)d_in[2];
    const float* y = (const float*)d_in[3];
    float* out = (float*)d_out;

    float* ws = (float*)d_ws;
    float* q0 = ws;                 // [2][NB][NPTS]  (q = pot + n2)
    float* q1 = ws + 2 * NE;
    float* Ls = ws + 4 * NE;        // [2][NB][NPTS]
    float* colBase = ws + 6 * NE;   // [2][NB][NPTS]
    float* partials = ws + 8 * NE;  // 1024 floats

    // eps annealing schedule (host-side, as in reference)
    double eps_list[32];
    int ne = 0;
    const double eps_final = 0.05 * 0.05;   // blur^p
    double eps = 2.0 * 2.0;                  // diameter^p
    while (eps > eps_final) { eps_list[ne++] = eps; eps *= 0.64; }  // scaling^p
    eps_list[ne++] = eps_final;              // ne == 18

    const float* qp = q0;
    float* qn = q1;

    auto phase = [&](double e, double e_prev, float c_old, float c_new,
                     int init, int fin) {
        sinkhorn_phase<<<1024, THREADS, 0, stream>>>(
            x, y, a, b, qp, qn, Ls, colBase, partials,
            (float)e, (float)(1.0 / e), c_old, c_new,
            (float)(e_prev / e), init, fin);
    };
    auto swapbuf = [&]() {
        const float* t = qp; qp = qn; qn = (float*)t;
    };

    // init at eps0 (mest=0 in-band; band check still guards correctness)
    phase(eps_list[0], eps_list[0], 0.0f, 1.0f, 1, 0);
    swapbuf();
    // annealed damped iterations
    double e_prev = eps_list[0];
    for (int k = 0; k < ne; k++) {
        phase(eps_list[k], e_prev, 0.5f, 0.5f, 0, 0);
        e_prev = eps_list[k];
        swapbuf();
    }
    // final extrapolation at eps_final (no damping) + fused partial loss
    phase(eps_list[ne - 1], e_prev, 0.0f, 1.0f, 0, 1);

    final_reduce<<<1, 512, 0, stream>>>(partials, out);
}

// Round 17
// 254.203 us; speedup vs baseline: 6.9279x; 1.0354x over previous
//
#include <hip/hip_runtime.h>
#include <cmath>

#define NB 8
#define NPTS 2048
#define NE (NB * NPTS)
#define THREADS 512
#define NPAIR 2   // packed row-pairs per wave -> 4 rows/wave, 32 rows/block, 1024 blocks

typedef float v2f __attribute__((ext_vector_type(2)));

#if defined(__has_builtin)
#if __has_builtin(__builtin_amdgcn_exp2f)
#define FAST_EXP2(x) __builtin_amdgcn_exp2f(x)
#else
#define FAST_EXP2(x) exp2f(x)
#endif
#if __has_builtin(__builtin_amdgcn_logf)
#define FAST_LOG2(x) __builtin_amdgcn_logf(x)
#else
#define FAST_LOG2(x) log2f(x)
#endif
#else
#define FAST_EXP2(x) exp2f(x)
#define FAST_LOG2(x) log2f(x)
#endif

// ---- DPP wave64 reductions (VALU pipe only; result valid at lane 63) ----
template<int CTRL>
__device__ __forceinline__ float dpp_f(float v) {
    return __int_as_float(__builtin_amdgcn_update_dpp(
        __float_as_int(v), __float_as_int(v), CTRL, 0xF, 0xF, false));
}
__device__ __forceinline__ float wred_max(float v) {
    v = fmaxf(v, dpp_f<0xB1>(v));
    v = fmaxf(v, dpp_f<0x4E>(v));
    v = fmaxf(v, dpp_f<0x141>(v));
    v = fmaxf(v, dpp_f<0x140>(v));
    v = fmaxf(v, dpp_f<0x142>(v));
    v = fmaxf(v, dpp_f<0x143>(v));
    return v;
}
__device__ __forceinline__ float wred_sum(float v) {
    v += dpp_f<0xB1>(v);
    v += dpp_f<0x4E>(v);
    v += dpp_f<0x141>(v);
    v += dpp_f<0x140>(v);
    v += dpp_f<0x142>(v);
    v += dpp_f<0x143>(v);
    return v;
}

// One Sinkhorn "phase" (R16 structure + s_setprio around compute body).
// Block remap: batch = hw & 7 -> all 128 blocks of a batch land on one XCD
// (round-robin dispatch), so ping-pong q/Ls/colBase traffic stays in that
// XCD's L2. q = pot + n2 (n2 = -|p|^2/2) is the state: steady staging is
// hc4 = fma(q4, sc, bse4) from two float4 streams. Stabilizer m_est =
// prev LSE * eps-ratio, band-validated (s in (1e-30,1e34)); exact
// wave-local 2-pass redo otherwise. setprio(1) over the exp-dense body
// lets compute-phase waves win arbitration over co-resident staging-phase
// waves (4 blocks/CU at staggered phases). finalPhase fuses loss partials.
__global__ __launch_bounds__(THREADS, 8) void sinkhorn_phase(
    const float* __restrict__ x, const float* __restrict__ y,
    const float* __restrict__ a, const float* __restrict__ b,
    const float* __restrict__ qR, float* __restrict__ qW,
    float* __restrict__ Ls,          // [2][NB][NPTS] log2-domain LSE store
    float* __restrict__ colBase,     // [2][NB][NPTS] log2(w_col), init-written
    float* __restrict__ partials,    // [1024] final-phase partial sums
    float eps, float inv_eps, float c_old, float c_new,
    float mscale, int initPhase, int finalPhase)
{
    __shared__ float4 xy4[NPTS / 2];   // 16 KB: {x_2k, y_2k, x_2k+1, y_2k+1}
    __shared__ float2 hc2[NPTS / 2];   // 8 KB: {hc_2k, hc_2k+1}
    __shared__ float pw[8];

    // XCD-aware remap (bijective on [0,1024)): batch = hw & 7 -> XCD b.
    const int hw = blockIdx.x;
    const int batch = hw & 7;
    const int pos = hw >> 3;            // 0..127
    const int side = pos >> 6;          // 64 row-tiles per side per batch
    const int rowTile = pos & 63;

    const float* rowPts = side ? y : x;
    const float* colPts = side ? x : y;
    const float* wcol   = side ? a : b;
    const float* wrow   = side ? b : a;

    const float LOG2E = 1.4426950408889634f;
    const float LN2 = 0.69314718055994531f;
    const float sc = inv_eps * LOG2E;

    // Stage xy: pure float4 copy (coalesced, no math).
    const float4* cp4 = ((const float4*)colPts) + (size_t)batch * (NPTS / 2);
    xy4[threadIdx.x]       = cp4[threadIdx.x];
    xy4[threadIdx.x + 512] = cp4[threadIdx.x + 512];

    // Stage hc.
    {
        float* hcs = (float*)hc2;
        if (initPhase) {
            const float2* cp2 = (const float2*)(colPts + (size_t)batch * NPTS * 2);
            const float* wl = wcol + (size_t)batch * NPTS;
            const int cOpp = (1 - side) * NE + batch * NPTS;
            #pragma unroll
            for (int k = 0; k < NPTS / THREADS; k++) {
                int j = threadIdx.x + k * THREADS;
                float2 p = cp2[j];
                float n2 = -0.5f * fmaf(p.x, p.x, p.y * p.y);
                float bsev = FAST_LOG2(wl[j]);
                hcs[j] = fmaf(n2, sc, bsev);
                if (rowTile == 0) colBase[cOpp + j] = bsev;
            }
        } else {
            const float4* qq = (const float4*)(qR + (1 - side) * NE + batch * NPTS);
            const float4* bb = (const float4*)(colBase + (1 - side) * NE + batch * NPTS);
            float4 qv = qq[threadIdx.x];
            float4 bv = bb[threadIdx.x];
            float4 h;
            h.x = fmaf(qv.x, sc, bv.x);
            h.y = fmaf(qv.y, sc, bv.y);
            h.z = fmaf(qv.z, sc, bv.z);
            h.w = fmaf(qv.w, sc, bv.w);
            ((float4*)hcs)[threadIdx.x] = h;
        }
    }
    __syncthreads();

    const int lane = threadIdx.x & 63;
    const int wv = threadIdx.x >> 6;        // 8 waves/block
    const int row0 = rowTile * 32 + wv * (2 * NPAIR);
    const int gidx0 = batch * NPTS + row0;
    const float2* rp2 = (const float2*)(rowPts + (size_t)batch * NPTS * 2) + row0;
    const float* Lp = Ls + side * NE + gidx0;

    v2f rxp[NPAIR], ryp[NPAIR], nmest[NPAIR], sp[NPAIR];
    #pragma unroll
    for (int p = 0; p < NPAIR; p++) {
        float2 p0 = rp2[2 * p];
        float2 p1 = rp2[2 * p + 1];
        rxp[p] = (v2f){p0.x * sc, p1.x * sc};
        ryp[p] = (v2f){p0.y * sc, p1.y * sc};
        float m0 = initPhase ? 0.0f : Lp[2 * p] * mscale;
        float m1 = initPhase ? 0.0f : Lp[2 * p + 1] * mscale;
        nmest[p] = (v2f){-m0, -m1};
        sp[p] = (v2f){0.0f, 0.0f};
    }

    __builtin_amdgcn_s_setprio(1);
    // Fused pass: 16 iters; per iter 2 cols x 4 rows = 8 elements.
    #pragma unroll 8
    for (int it = 0; it < NPTS / 128; it++) {
        float4 v = xy4[(it << 6) + lane];
        float2 h = hc2[(it << 6) + lane];
        #pragma unroll
        for (int p = 0; p < NPAIR; p++) {
            v2f h0 = (v2f){h.x, h.x} + nmest[p];
            v2f h1 = (v2f){h.y, h.y} + nmest[p];
            v2f t0 = __builtin_elementwise_fma(rxp[p], (v2f){v.x, v.x},
                        __builtin_elementwise_fma(ryp[p], (v2f){v.y, v.y}, h0));
            v2f t1 = __builtin_elementwise_fma(rxp[p], (v2f){v.z, v.z},
                        __builtin_elementwise_fma(ryp[p], (v2f){v.w, v.w}, h1));
            sp[p] += (v2f){FAST_EXP2(t0.x), FAST_EXP2(t0.y)};
            sp[p] += (v2f){FAST_EXP2(t1.x), FAST_EXP2(t1.y)};
        }
    }
    float s[4];
    #pragma unroll
    for (int p = 0; p < NPAIR; p++) {
        s[2 * p]     = wred_sum(sp[p].x);
        s[2 * p + 1] = wred_sum(sp[p].y);
    }
    __builtin_amdgcn_s_setprio(0);

    int bad = 0;
    if (lane == 63) {
        #pragma unroll
        for (int r = 0; r < 4; r++)
            bad |= !(s[r] > 1e-30f && s[r] < 1e34f);
    }
    float mesc[4];
    #pragma unroll
    for (int p = 0; p < NPAIR; p++) {
        mesc[2 * p] = -nmest[p].x; mesc[2 * p + 1] = -nmest[p].y;
    }

    if (__any(bad)) {
        // Exact 2-pass redo (wave-local; no barrier needed).
        __builtin_amdgcn_s_setprio(1);
        v2f mm[NPAIR];
        #pragma unroll
        for (int p = 0; p < NPAIR; p++) mm[p] = (v2f){-3.4e38f, -3.4e38f};
        #pragma unroll 4
        for (int it = 0; it < NPTS / 128; it++) {
            float4 v = xy4[(it << 6) + lane];
            float2 h = hc2[(it << 6) + lane];
            #pragma unroll
            for (int p = 0; p < NPAIR; p++) {
                v2f h0 = (v2f){h.x, h.x} + nmest[p];
                v2f h1 = (v2f){h.y, h.y} + nmest[p];
                v2f t0 = __builtin_elementwise_fma(rxp[p], (v2f){v.x, v.x},
                            __builtin_elementwise_fma(ryp[p], (v2f){v.y, v.y}, h0));
                v2f t1 = __builtin_elementwise_fma(rxp[p], (v2f){v.z, v.z},
                            __builtin_elementwise_fma(ryp[p], (v2f){v.w, v.w}, h1));
                mm[p] = __builtin_elementwise_max(mm[p],
                            __builtin_elementwise_max(t0, t1));
            }
        }
        float mmsc[4];
        #pragma unroll
        for (int p = 0; p < NPAIR; p++) {
            mmsc[2 * p] = mm[p].x; mmsc[2 * p + 1] = mm[p].y;
        }
        #pragma unroll
        for (int r = 0; r < 4; r++) {
            mmsc[r] = wred_max(mmsc[r]);
            mmsc[r] = __shfl(mmsc[r], 63);
        }
        v2f mmb[NPAIR];
        #pragma unroll
        for (int p = 0; p < NPAIR; p++) {
            mmb[p] = (v2f){mmsc[2 * p], mmsc[2 * p + 1]};
            sp[p] = (v2f){0.0f, 0.0f};
        }
        #pragma unroll 4
        for (int it = 0; it < NPTS / 128; it++) {
            float4 v = xy4[(it << 6) + lane];
            float2 h = hc2[(it << 6) + lane];
            #pragma unroll
            for (int p = 0; p < NPAIR; p++) {
                v2f h0 = (v2f){h.x, h.x} + nmest[p] - mmb[p];
                v2f h1 = (v2f){h.y, h.y} + nmest[p] - mmb[p];
                v2f t0 = __builtin_elementwise_fma(rxp[p], (v2f){v.x, v.x},
                            __builtin_elementwise_fma(ryp[p], (v2f){v.y, v.y}, h0));
                v2f t1 = __builtin_elementwise_fma(rxp[p], (v2f){v.z, v.z},
                            __builtin_elementwise_fma(ryp[p], (v2f){v.w, v.w}, h1));
                sp[p] += (v2f){FAST_EXP2(t0.x), FAST_EXP2(t0.y)};
                sp[p] += (v2f){FAST_EXP2(t1.x), FAST_EXP2(t1.y)};
            }
        }
        #pragma unroll
        for (int p = 0; p < NPAIR; p++) {
            s[2 * p]     = wred_sum(sp[p].x);
            s[2 * p + 1] = wred_sum(sp[p].y);
            mesc[2 * p] += mmb[p].x;
            mesc[2 * p + 1] += mmb[p].y;
        }
        __builtin_amdgcn_s_setprio(0);
    }

    if (lane == 63) {
        float4 qout, Lout;
        float part = 0.0f;
        float4 qprev = {0.0f, 0.0f, 0.0f, 0.0f};
        if (!initPhase && c_old != 0.0f)
            qprev = *(const float4*)&qR[side * NE + gidx0];
        const float* qpv = (const float*)&qprev;
        float* qo = (float*)&qout;
        float* Lo = (float*)&Lout;
        #pragma unroll
        for (int r = 0; r < 4; r++) {
            float2 p = rp2[r];
            float n2o = -0.5f * fmaf(p.x, p.x, p.y * p.y);
            float L = mesc[r] + FAST_LOG2(s[r]);
            float sm = -eps * LN2 * fmaf(n2o, sc, L);     // -eps*ln2*(hr + L)
            float fprev = qpv[r] - n2o;
            float fnew = c_old * fprev + c_new * sm;
            qo[r] = fnew + n2o;
            Lo[r] = L;
            if (finalPhase) part += wrow[gidx0 + r] * fnew;
        }
        *(float4*)&qW[side * NE + gidx0] = qout;
        *(float4*)&Ls[side * NE + gidx0] = Lout;
        if (finalPhase) pw[wv] = part;
    }
    if (finalPhase) {
        __syncthreads();
        if (threadIdx.x == 0) {
            float t = 0.0f;
            #pragma unroll
            for (int i = 0; i < 8; i++) t += pw[i];
            partials[hw] = t;
        }
    }
}

__global__ __launch_bounds__(512) void final_reduce(
    const float* __restrict__ partials, float* __restrict__ out)
{
    float v = partials[threadIdx.x] + partials[threadIdx.x + 512];
    v += __shfl_xor(v, 32);
    v += __shfl_xor(v, 16);
    v += __shfl_xor(v, 8);
    v += __shfl_xor(v, 4);
    v += __shfl_xor(v, 2);
    v += __shfl_xor(v, 1);
    __shared__ float ws8[8];
    if ((threadIdx.x & 63) == 0) ws8[threadIdx.x >> 6] = v;
    __syncthreads();
    if (threadIdx.x == 0) {
        float t = 0.0f;
        #pragma unroll
        for (int i = 0; i < 8; i++) t += ws8[i];
        out[0] = t * (1.0f / NB);
    }
}

extern "C" void kernel_launch(void* const* d_in, const int* in_sizes, int n_in,
                              void* d_out, int out_size, void* d_ws, size_t ws_size,
                              hipStream_t stream)
{
    const float* a = (const float*)d_in[0];
    const float* x = (const float*)d_in[1];
    const float* b = (const float*)d_in[2];
    const float* y = (const float*)d_in[3];
    float* out = (float*)d_out;

    float* ws = (float*)d_ws;
    float* q0 = ws;                 // [2][NB][NPTS]  (q = pot + n2)
    float* q1 = ws + 2 * NE;
    float* Ls = ws + 4 * NE;        // [2][NB][NPTS]
    float* colBase = ws + 6 * NE;   // [2][NB][NPTS]
    float* partials = ws + 8 * NE;  // 1024 floats

    // eps annealing schedule (host-side, as in reference)
    double eps_list[32];
    int ne = 0;
    const double eps_final = 0.05 * 0.05;   // blur^p
    double eps = 2.0 * 2.0;                  // diameter^p
    while (eps > eps_final) { eps_list[ne++] = eps; eps *= 0.64; }  // scaling^p
    eps_list[ne++] = eps_final;              // ne == 18

    const float* qp = q0;
    float* qn = q1;

    auto phase = [&](double e, double e_prev, float c_old, float c_new,
                     int init, int fin) {
        sinkhorn_phase<<<1024, THREADS, 0, stream>>>(
            x, y, a, b, qp, qn, Ls, colBase, partials,
            (float)e, (float)(1.0 / e), c_old, c_new,
            (float)(e_prev / e), init, fin);
    };
    auto swapbuf = [&]() {
        const float* t = qp; qp = qn; qn = (float*)t;
    };

    // init at eps0 (mest=0 in-band; band check still guards correctness)
    phase(eps_list[0], eps_list[0], 0.0f, 1.0f, 1, 0);
    swapbuf();
    // annealed damped iterations
    double e_prev = eps_list[0];
    for (int k = 0; k < ne; k++) {
        phase(eps_list[k], e_prev, 0.5f, 0.5f, 0, 0);
        e_prev = eps_list[k];
        swapbuf();
    }
    // final extrapolation at eps_final (no damping) + fused partial loss
    phase(eps_list[ne - 1], e_prev, 0.0f, 1.0f, 0, 1);

    final_reduce<<<1, 512, 0, stream>>>(partials, out);
}

// Round 18
// 251.998 us; speedup vs baseline: 6.9885x; 1.0088x over previous
//
#include <hip/hip_runtime.h>
#include <cmath>

#define NB 8
#define NPTS 2048
#define NE (NB * NPTS)
#define THREADS 512
#define NPAIR 2   // packed row-pairs per wave -> 4 rows/wave, 32 rows/block, 1024 blocks

typedef float v2f __attribute__((ext_vector_type(2)));

#if defined(__has_builtin)
#if __has_builtin(__builtin_amdgcn_exp2f)
#define FAST_EXP2(x) __builtin_amdgcn_exp2f(x)
#else
#define FAST_EXP2(x) exp2f(x)
#endif
#if __has_builtin(__builtin_amdgcn_logf)
#define FAST_LOG2(x) __builtin_amdgcn_logf(x)
#else
#define FAST_LOG2(x) log2f(x)
#endif
#else
#define FAST_EXP2(x) exp2f(x)
#define FAST_LOG2(x) log2f(x)
#endif

// ---- DPP wave64 reductions (VALU pipe only; result valid at lane 63) ----
template<int CTRL>
__device__ __forceinline__ float dpp_f(float v) {
    return __int_as_float(__builtin_amdgcn_update_dpp(
        __float_as_int(v), __float_as_int(v), CTRL, 0xF, 0xF, false));
}
__device__ __forceinline__ float wred_max(float v) {
    v = fmaxf(v, dpp_f<0xB1>(v));
    v = fmaxf(v, dpp_f<0x4E>(v));
    v = fmaxf(v, dpp_f<0x141>(v));
    v = fmaxf(v, dpp_f<0x140>(v));
    v = fmaxf(v, dpp_f<0x142>(v));
    v = fmaxf(v, dpp_f<0x143>(v));
    return v;
}
__device__ __forceinline__ float wred_sum(float v) {
    v += dpp_f<0xB1>(v);
    v += dpp_f<0x4E>(v);
    v += dpp_f<0x141>(v);
    v += dpp_f<0x140>(v);
    v += dpp_f<0x142>(v);
    v += dpp_f<0x143>(v);
    return v;
}

// One Sinkhorn "phase" (R17 + producer-computed hc: H-buffer staging).
// H[t][j] = fma(q_t[j], sc_of_this_phase, log2 w_t[j]) is written by the
// PREVIOUS phase's epilogue (sc_next is a host constant), so steady staging
// is a single float4 stream copied into LDS (no math, one latency chain).
// H ping-pongs like q. XCD remap: batch = hw & 7 keeps a batch's traffic
// on one XCD's L2. Stabilizer m_est = prev LSE * eps-ratio, band-validated
// (s in (1e-30,1e34)); exact wave-local 2-pass redo otherwise. setprio(1)
// over the exp-dense body. finalPhase fuses loss partials.
__global__ __launch_bounds__(THREADS, 8) void sinkhorn_phase(
    const float* __restrict__ x, const float* __restrict__ y,
    const float* __restrict__ a, const float* __restrict__ b,
    const float* __restrict__ qR, float* __restrict__ qW,
    const float* __restrict__ HR, float* __restrict__ HW,
    float* __restrict__ Ls,          // [2][NB][NPTS] log2-domain LSE store
    float* __restrict__ colBase,     // [2][NB][NPTS] log2(w_side), init-written
    float* __restrict__ partials,    // [1024] final-phase partial sums
    float eps, float inv_eps, float c_old, float c_new,
    float scNext,                    // (1/eps_next)*log2e for H write
    float mscale, int initPhase, int finalPhase)
{
    __shared__ float4 xy4[NPTS / 2];   // 16 KB: {x_2k, y_2k, x_2k+1, y_2k+1}
    __shared__ float2 hc2[NPTS / 2];   // 8 KB: {hc_2k, hc_2k+1}
    __shared__ float pw[8];

    // XCD-aware remap (bijective on [0,1024)): batch = hw & 7 -> XCD b.
    const int hw = blockIdx.x;
    const int batch = hw & 7;
    const int pos = hw >> 3;            // 0..127
    const int side = pos >> 6;          // 64 row-tiles per side per batch
    const int rowTile = pos & 63;

    const float* rowPts = side ? y : x;
    const float* colPts = side ? x : y;
    const float* wcol   = side ? a : b;
    const float* wrow   = side ? b : a;

    const float LOG2E = 1.4426950408889634f;
    const float LN2 = 0.69314718055994531f;
    const float sc = inv_eps * LOG2E;

    // Stage xy: pure float4 copy (coalesced, no math).
    const float4* cp4 = ((const float4*)colPts) + (size_t)batch * (NPTS / 2);
    xy4[threadIdx.x]       = cp4[threadIdx.x];
    xy4[threadIdx.x + 512] = cp4[threadIdx.x + 512];

    // Stage hc.
    {
        float* hcs = (float*)hc2;
        if (initPhase) {
            const float2* cp2 = (const float2*)(colPts + (size_t)batch * NPTS * 2);
            const float* wl = wcol + (size_t)batch * NPTS;
            const int cOpp = (1 - side) * NE + batch * NPTS;
            #pragma unroll
            for (int k = 0; k < NPTS / THREADS; k++) {
                int j = threadIdx.x + k * THREADS;
                float2 p = cp2[j];
                float n2 = -0.5f * fmaf(p.x, p.x, p.y * p.y);
                float bsev = FAST_LOG2(wl[j]);
                hcs[j] = fmaf(n2, sc, bsev);
                if (rowTile == 0) colBase[cOpp + j] = bsev;
            }
        } else {
            const float4* Hr = (const float4*)(HR + (1 - side) * NE + batch * NPTS);
            ((float4*)hcs)[threadIdx.x] = Hr[threadIdx.x];
        }
    }
    __syncthreads();

    const int lane = threadIdx.x & 63;
    const int wv = threadIdx.x >> 6;        // 8 waves/block
    const int row0 = rowTile * 32 + wv * (2 * NPAIR);
    const int gidx0 = batch * NPTS + row0;
    const float2* rp2 = (const float2*)(rowPts + (size_t)batch * NPTS * 2) + row0;
    const float* Lp = Ls + side * NE + gidx0;

    v2f rxp[NPAIR], ryp[NPAIR], nmest[NPAIR], sp[NPAIR];
    #pragma unroll
    for (int p = 0; p < NPAIR; p++) {
        float2 p0 = rp2[2 * p];
        float2 p1 = rp2[2 * p + 1];
        rxp[p] = (v2f){p0.x * sc, p1.x * sc};
        ryp[p] = (v2f){p0.y * sc, p1.y * sc};
        float m0 = initPhase ? 0.0f : Lp[2 * p] * mscale;
        float m1 = initPhase ? 0.0f : Lp[2 * p + 1] * mscale;
        nmest[p] = (v2f){-m0, -m1};
        sp[p] = (v2f){0.0f, 0.0f};
    }

    __builtin_amdgcn_s_setprio(1);
    // Fused pass: 16 iters; per iter 2 cols x 4 rows = 8 elements.
    #pragma unroll 8
    for (int it = 0; it < NPTS / 128; it++) {
        float4 v = xy4[(it << 6) + lane];
        float2 h = hc2[(it << 6) + lane];
        #pragma unroll
        for (int p = 0; p < NPAIR; p++) {
            v2f h0 = (v2f){h.x, h.x} + nmest[p];
            v2f h1 = (v2f){h.y, h.y} + nmest[p];
            v2f t0 = __builtin_elementwise_fma(rxp[p], (v2f){v.x, v.x},
                        __builtin_elementwise_fma(ryp[p], (v2f){v.y, v.y}, h0));
            v2f t1 = __builtin_elementwise_fma(rxp[p], (v2f){v.z, v.z},
                        __builtin_elementwise_fma(ryp[p], (v2f){v.w, v.w}, h1));
            sp[p] += (v2f){FAST_EXP2(t0.x), FAST_EXP2(t0.y)};
            sp[p] += (v2f){FAST_EXP2(t1.x), FAST_EXP2(t1.y)};
        }
    }
    float s[4];
    #pragma unroll
    for (int p = 0; p < NPAIR; p++) {
        s[2 * p]     = wred_sum(sp[p].x);
        s[2 * p + 1] = wred_sum(sp[p].y);
    }
    __builtin_amdgcn_s_setprio(0);

    int bad = 0;
    if (lane == 63) {
        #pragma unroll
        for (int r = 0; r < 4; r++)
            bad |= !(s[r] > 1e-30f && s[r] < 1e34f);
    }
    float mesc[4];
    #pragma unroll
    for (int p = 0; p < NPAIR; p++) {
        mesc[2 * p] = -nmest[p].x; mesc[2 * p + 1] = -nmest[p].y;
    }

    if (__any(bad)) {
        // Exact 2-pass redo (wave-local; no barrier needed).
        __builtin_amdgcn_s_setprio(1);
        v2f mm[NPAIR];
        #pragma unroll
        for (int p = 0; p < NPAIR; p++) mm[p] = (v2f){-3.4e38f, -3.4e38f};
        #pragma unroll 4
        for (int it = 0; it < NPTS / 128; it++) {
            float4 v = xy4[(it << 6) + lane];
            float2 h = hc2[(it << 6) + lane];
            #pragma unroll
            for (int p = 0; p < NPAIR; p++) {
                v2f h0 = (v2f){h.x, h.x} + nmest[p];
                v2f h1 = (v2f){h.y, h.y} + nmest[p];
                v2f t0 = __builtin_elementwise_fma(rxp[p], (v2f){v.x, v.x},
                            __builtin_elementwise_fma(ryp[p], (v2f){v.y, v.y}, h0));
                v2f t1 = __builtin_elementwise_fma(rxp[p], (v2f){v.z, v.z},
                            __builtin_elementwise_fma(ryp[p], (v2f){v.w, v.w}, h1));
                mm[p] = __builtin_elementwise_max(mm[p],
                            __builtin_elementwise_max(t0, t1));
            }
        }
        float mmsc[4];
        #pragma unroll
        for (int p = 0; p < NPAIR; p++) {
            mmsc[2 * p] = mm[p].x; mmsc[2 * p + 1] = mm[p].y;
        }
        #pragma unroll
        for (int r = 0; r < 4; r++) {
            mmsc[r] = wred_max(mmsc[r]);
            mmsc[r] = __shfl(mmsc[r], 63);
        }
        v2f mmb[NPAIR];
        #pragma unroll
        for (int p = 0; p < NPAIR; p++) {
            mmb[p] = (v2f){mmsc[2 * p], mmsc[2 * p + 1]};
            sp[p] = (v2f){0.0f, 0.0f};
        }
        #pragma unroll 4
        for (int it = 0; it < NPTS / 128; it++) {
            float4 v = xy4[(it << 6) + lane];
            float2 h = hc2[(it << 6) + lane];
            #pragma unroll
            for (int p = 0; p < NPAIR; p++) {
                v2f h0 = (v2f){h.x, h.x} + nmest[p] - mmb[p];
                v2f h1 = (v2f){h.y, h.y} + nmest[p] - mmb[p];
                v2f t0 = __builtin_elementwise_fma(rxp[p], (v2f){v.x, v.x},
                            __builtin_elementwise_fma(ryp[p], (v2f){v.y, v.y}, h0));
                v2f t1 = __builtin_elementwise_fma(rxp[p], (v2f){v.z, v.z},
                            __builtin_elementwise_fma(ryp[p], (v2f){v.w, v.w}, h1));
                sp[p] += (v2f){FAST_EXP2(t0.x), FAST_EXP2(t0.y)};
                sp[p] += (v2f){FAST_EXP2(t1.x), FAST_EXP2(t1.y)};
            }
        }
        #pragma unroll
        for (int p = 0; p < NPAIR; p++) {
            s[2 * p]     = wred_sum(sp[p].x);
            s[2 * p + 1] = wred_sum(sp[p].y);
            mesc[2 * p] += mmb[p].x;
            mesc[2 * p + 1] += mmb[p].y;
        }
        __builtin_amdgcn_s_setprio(0);
    }

    if (lane == 63) {
        float4 qout, Lout, Hout;
        float part = 0.0f;
        float4 qprev = {0.0f, 0.0f, 0.0f, 0.0f};
        if (!initPhase && c_old != 0.0f)
            qprev = *(const float4*)&qR[side * NE + gidx0];
        float4 bse4;
        if (initPhase) {
            bse4.x = FAST_LOG2(wrow[gidx0]);
            bse4.y = FAST_LOG2(wrow[gidx0 + 1]);
            bse4.z = FAST_LOG2(wrow[gidx0 + 2]);
            bse4.w = FAST_LOG2(wrow[gidx0 + 3]);
        } else if (!finalPhase) {
            bse4 = *(const float4*)&colBase[side * NE + gidx0];
        }
        const float* qpv = (const float*)&qprev;
        const float* bs = (const float*)&bse4;
        float* qo = (float*)&qout;
        float* Lo = (float*)&Lout;
        float* Ho = (float*)&Hout;
        #pragma unroll
        for (int r = 0; r < 4; r++) {
            float2 p = rp2[r];
            float n2o = -0.5f * fmaf(p.x, p.x, p.y * p.y);
            float L = mesc[r] + FAST_LOG2(s[r]);
            float sm = -eps * LN2 * fmaf(n2o, sc, L);     // -eps*ln2*(hr + L)
            float fprev = qpv[r] - n2o;
            float fnew = c_old * fprev + c_new * sm;
            qo[r] = fnew + n2o;
            Lo[r] = L;
            Ho[r] = fmaf(qo[r], scNext, bs[r]);
            if (finalPhase) part += wrow[gidx0 + r] * fnew;
        }
        *(float4*)&qW[side * NE + gidx0] = qout;
        *(float4*)&Ls[side * NE + gidx0] = Lout;
        if (!finalPhase) *(float4*)&HW[side * NE + gidx0] = Hout;
        if (finalPhase) pw[wv] = part;
    }
    if (finalPhase) {
        __syncthreads();
        if (threadIdx.x == 0) {
            float t = 0.0f;
            #pragma unroll
            for (int i = 0; i < 8; i++) t += pw[i];
            partials[hw] = t;
        }
    }
}

__global__ __launch_bounds__(512) void final_reduce(
    const float* __restrict__ partials, float* __restrict__ out)
{
    float v = partials[threadIdx.x] + partials[threadIdx.x + 512];
    v += __shfl_xor(v, 32);
    v += __shfl_xor(v, 16);
    v += __shfl_xor(v, 8);
    v += __shfl_xor(v, 4);
    v += __shfl_xor(v, 2);
    v += __shfl_xor(v, 1);
    __shared__ float ws8[8];
    if ((threadIdx.x & 63) == 0) ws8[threadIdx.x >> 6] = v;
    __syncthreads();
    if (threadIdx.x == 0) {
        float t = 0.0f;
        #pragma unroll
        for (int i = 0; i < 8; i++) t += ws8[i];
        out[0] = t * (1.0f / NB);
    }
}

extern "C" void kernel_launch(void* const* d_in, const int* in_sizes, int n_in,
                              void* d_out, int out_size, void* d_ws, size_t ws_size,
                              hipStream_t stream)
{
    const float* a = (const float*)d_in[0];
    const float* x = (const float*)d_in[1];
    const float* b = (const float*)d_in[2];
    const float* y = (const float*)d_in[3];
    float* out = (float*)d_out;

    float* ws = (float*)d_ws;
    float* q0 = ws;                 // [2][NB][NPTS]  (q = pot + n2)
    float* q1 = ws + 2 * NE;
    float* H0 = ws + 4 * NE;        // [2][NB][NPTS]  (H = fma(q, sc, bse))
    float* H1 = ws + 6 * NE;
    float* Ls = ws + 8 * NE;        // [2][NB][NPTS]
    float* colBase = ws + 10 * NE;  // [2][NB][NPTS]
    float* partials = ws + 12 * NE; // 1024 floats

    // eps annealing schedule (host-side, as in reference)
    double eps_list[32];
    int ne = 0;
    const double eps_final = 0.05 * 0.05;   // blur^p
    double eps = 2.0 * 2.0;                  // diameter^p
    while (eps > eps_final) { eps_list[ne++] = eps; eps *= 0.64; }  // scaling^p
    eps_list[ne++] = eps_final;              // ne == 18

    const float LOG2E_H = 1.4426950408889634f;
    const float* qp = q0; float* qn = q1;
    const float* Hp = H0; float* Hn = H1;

    auto phase = [&](double e, double e_prev, double e_next,
                     float c_old, float c_new, int init, int fin) {
        sinkhorn_phase<<<1024, THREADS, 0, stream>>>(
            x, y, a, b, qp, qn, Hp, Hn, Ls, colBase, partials,
            (float)e, (float)(1.0 / e), c_old, c_new,
            (float)((1.0 / e_next) * LOG2E_H),
            (float)(e_prev / e), init, fin);
    };
    auto swapbuf = [&]() {
        const float* t = qp; qp = qn; qn = (float*)t;
        const float* h = Hp; Hp = Hn; Hn = (float*)h;
    };

    // init at eps0 (mest=0 in-band; band check still guards correctness)
    phase(eps_list[0], eps_list[0], eps_list[0], 0.0f, 1.0f, 1, 0);
    swapbuf();
    // annealed damped iterations
    double e_prev = eps_list[0];
    for (int k = 0; k < ne; k++) {
        double e_next = (k + 1 < ne) ? eps_list[k + 1] : eps_list[ne - 1];
        phase(eps_list[k], e_prev, e_next, 0.5f, 0.5f, 0, 0);
        e_prev = eps_list[k];
        swapbuf();
    }
    // final extrapolation at eps_final (no damping) + fused partial loss
    phase(eps_list[ne - 1], e_prev, eps_list[ne - 1], 0.0f, 1.0f, 0, 1);

    final_reduce<<<1, 512, 0, stream>>>(partials, out);
}

// Round 19
// 249.740 us; speedup vs baseline: 7.0517x; 1.0090x over previous
//
#include <hip/hip_runtime.h>
#include <cmath>

#define NB 8
#define NPTS 2048
#define NE (NB * NPTS)
#define THREADS 512
#define NPAIR 2   // packed row-pairs per wave -> 4 rows/wave, 32 rows/block, 1024 blocks

typedef float v2f __attribute__((ext_vector_type(2)));

#if defined(__has_builtin)
#if __has_builtin(__builtin_amdgcn_exp2f)
#define FAST_EXP2(x) __builtin_amdgcn_exp2f(x)
#else
#define FAST_EXP2(x) exp2f(x)
#endif
#if __has_builtin(__builtin_amdgcn_logf)
#define FAST_LOG2(x) __builtin_amdgcn_logf(x)
#else
#define FAST_LOG2(x) log2f(x)
#endif
#else
#define FAST_EXP2(x) exp2f(x)
#define FAST_LOG2(x) log2f(x)
#endif

// ---- DPP wave64 reductions (VALU pipe only; result valid at lane 63) ----
template<int CTRL>
__device__ __forceinline__ float dpp_f(float v) {
    return __int_as_float(__builtin_amdgcn_update_dpp(
        __float_as_int(v), __float_as_int(v), CTRL, 0xF, 0xF, false));
}
__device__ __forceinline__ float wred_max(float v) {
    v = fmaxf(v, dpp_f<0xB1>(v));
    v = fmaxf(v, dpp_f<0x4E>(v));
    v = fmaxf(v, dpp_f<0x141>(v));
    v = fmaxf(v, dpp_f<0x140>(v));
    v = fmaxf(v, dpp_f<0x142>(v));
    v = fmaxf(v, dpp_f<0x143>(v));
    return v;
}
__device__ __forceinline__ float wred_sum(float v) {
    v += dpp_f<0xB1>(v);
    v += dpp_f<0x4E>(v);
    v += dpp_f<0x141>(v);
    v += dpp_f<0x140>(v);
    v += dpp_f<0x142>(v);
    v += dpp_f<0x143>(v);
    return v;
}

// One Sinkhorn "phase" (R18 + hoisted epilogue loads + dead-store elim).
// H[t][j] = fma(q_t[j], sc_of_this_phase, log2 w_t[j]) written by the
// PREVIOUS phase's epilogue -> steady staging is one float4 stream to LDS.
// XCD remap: batch = hw & 7 keeps a batch's traffic on one XCD's L2.
// Stabilizer m_est = prev LSE * eps-ratio, band-validated (s in
// (1e-30,1e34)); exact wave-local 2-pass redo otherwise. setprio(1) over
// the exp-dense body. Epilogue operands (qprev, bse) preloaded BEFORE the
// compute body so their latency hides under it. finalPhase: loss partials
// only (q/Ls/H stores dead, skipped).
__global__ __launch_bounds__(THREADS, 8) void sinkhorn_phase(
    const float* __restrict__ x, const float* __restrict__ y,
    const float* __restrict__ a, const float* __restrict__ b,
    const float* __restrict__ qR, float* __restrict__ qW,
    const float* __restrict__ HR, float* __restrict__ HW,
    float* __restrict__ Ls,          // [2][NB][NPTS] log2-domain LSE store
    float* __restrict__ colBase,     // [2][NB][NPTS] log2(w_side), init-written
    float* __restrict__ partials,    // [1024] final-phase partial sums
    float eps, float inv_eps, float c_old, float c_new,
    float scNext,                    // (1/eps_next)*log2e for H write
    float mscale, int initPhase, int finalPhase)
{
    __shared__ float4 xy4[NPTS / 2];   // 16 KB: {x_2k, y_2k, x_2k+1, y_2k+1}
    __shared__ float2 hc2[NPTS / 2];   // 8 KB: {hc_2k, hc_2k+1}
    __shared__ float pw[8];

    // XCD-aware remap (bijective on [0,1024)): batch = hw & 7 -> XCD b.
    const int hw = blockIdx.x;
    const int batch = hw & 7;
    const int pos = hw >> 3;            // 0..127
    const int side = pos >> 6;          // 64 row-tiles per side per batch
    const int rowTile = pos & 63;

    const float* rowPts = side ? y : x;
    const float* colPts = side ? x : y;
    const float* wcol   = side ? a : b;
    const float* wrow   = side ? b : a;

    const float LOG2E = 1.4426950408889634f;
    const float LN2 = 0.69314718055994531f;
    const float sc = inv_eps * LOG2E;

    // Stage xy: pure float4 copy (coalesced, no math).
    const float4* cp4 = ((const float4*)colPts) + (size_t)batch * (NPTS / 2);
    xy4[threadIdx.x]       = cp4[threadIdx.x];
    xy4[threadIdx.x + 512] = cp4[threadIdx.x + 512];

    // Stage hc.
    {
        float* hcs = (float*)hc2;
        if (initPhase) {
            const float2* cp2 = (const float2*)(colPts + (size_t)batch * NPTS * 2);
            const float* wl = wcol + (size_t)batch * NPTS;
            const int cOpp = (1 - side) * NE + batch * NPTS;
            #pragma unroll
            for (int k = 0; k < NPTS / THREADS; k++) {
                int j = threadIdx.x + k * THREADS;
                float2 p = cp2[j];
                float n2 = -0.5f * fmaf(p.x, p.x, p.y * p.y);
                float bsev = FAST_LOG2(wl[j]);
                hcs[j] = fmaf(n2, sc, bsev);
                if (rowTile == 0) colBase[cOpp + j] = bsev;
            }
        } else {
            const float4* Hr = (const float4*)(HR + (1 - side) * NE + batch * NPTS);
            ((float4*)hcs)[threadIdx.x] = Hr[threadIdx.x];
        }
    }
    __syncthreads();

    const int lane = threadIdx.x & 63;
    const int wv = threadIdx.x >> 6;        // 8 waves/block
    const int row0 = rowTile * 32 + wv * (2 * NPAIR);
    const int gidx0 = batch * NPTS + row0;
    const float2* rp2 = (const float2*)(rowPts + (size_t)batch * NPTS * 2) + row0;
    const float* Lp = Ls + side * NE + gidx0;

    v2f rxp[NPAIR], ryp[NPAIR], nmest[NPAIR], sp[NPAIR];
    float n2o[4];
    #pragma unroll
    for (int p = 0; p < NPAIR; p++) {
        float2 p0 = rp2[2 * p];
        float2 p1 = rp2[2 * p + 1];
        n2o[2 * p]     = -0.5f * fmaf(p0.x, p0.x, p0.y * p0.y);
        n2o[2 * p + 1] = -0.5f * fmaf(p1.x, p1.x, p1.y * p1.y);
        rxp[p] = (v2f){p0.x * sc, p1.x * sc};
        ryp[p] = (v2f){p0.y * sc, p1.y * sc};
        float m0 = initPhase ? 0.0f : Lp[2 * p] * mscale;
        float m1 = initPhase ? 0.0f : Lp[2 * p + 1] * mscale;
        nmest[p] = (v2f){-m0, -m1};
        sp[p] = (v2f){0.0f, 0.0f};
    }

    // Preload epilogue operands (lane 63) BEFORE compute: latency hides.
    float4 qprev4 = {0.0f, 0.0f, 0.0f, 0.0f};
    float4 bse4 = {0.0f, 0.0f, 0.0f, 0.0f};
    if (lane == 63 && !initPhase) {
        qprev4 = *(const float4*)&qR[side * NE + gidx0];
        bse4 = *(const float4*)&colBase[side * NE + gidx0];
    }

    __builtin_amdgcn_s_setprio(1);
    // Fused pass: 16 iters; per iter 2 cols x 4 rows = 8 elements.
    #pragma unroll 8
    for (int it = 0; it < NPTS / 128; it++) {
        float4 v = xy4[(it << 6) + lane];
        float2 h = hc2[(it << 6) + lane];
        #pragma unroll
        for (int p = 0; p < NPAIR; p++) {
            v2f h0 = (v2f){h.x, h.x} + nmest[p];
            v2f h1 = (v2f){h.y, h.y} + nmest[p];
            v2f t0 = __builtin_elementwise_fma(rxp[p], (v2f){v.x, v.x},
                        __builtin_elementwise_fma(ryp[p], (v2f){v.y, v.y}, h0));
            v2f t1 = __builtin_elementwise_fma(rxp[p], (v2f){v.z, v.z},
                        __builtin_elementwise_fma(ryp[p], (v2f){v.w, v.w}, h1));
            sp[p] += (v2f){FAST_EXP2(t0.x), FAST_EXP2(t0.y)};
            sp[p] += (v2f){FAST_EXP2(t1.x), FAST_EXP2(t1.y)};
        }
    }
    float s[4];
    #pragma unroll
    for (int p = 0; p < NPAIR; p++) {
        s[2 * p]     = wred_sum(sp[p].x);
        s[2 * p + 1] = wred_sum(sp[p].y);
    }
    __builtin_amdgcn_s_setprio(0);

    int bad = 0;
    if (lane == 63) {
        #pragma unroll
        for (int r = 0; r < 4; r++)
            bad |= !(s[r] > 1e-30f && s[r] < 1e34f);
    }
    float mesc[4];
    #pragma unroll
    for (int p = 0; p < NPAIR; p++) {
        mesc[2 * p] = -nmest[p].x; mesc[2 * p + 1] = -nmest[p].y;
    }

    if (__any(bad)) {
        // Exact 2-pass redo (wave-local; no barrier needed).
        __builtin_amdgcn_s_setprio(1);
        v2f mm[NPAIR];
        #pragma unroll
        for (int p = 0; p < NPAIR; p++) mm[p] = (v2f){-3.4e38f, -3.4e38f};
        #pragma unroll 4
        for (int it = 0; it < NPTS / 128; it++) {
            float4 v = xy4[(it << 6) + lane];
            float2 h = hc2[(it << 6) + lane];
            #pragma unroll
            for (int p = 0; p < NPAIR; p++) {
                v2f h0 = (v2f){h.x, h.x} + nmest[p];
                v2f h1 = (v2f){h.y, h.y} + nmest[p];
                v2f t0 = __builtin_elementwise_fma(rxp[p], (v2f){v.x, v.x},
                            __builtin_elementwise_fma(ryp[p], (v2f){v.y, v.y}, h0));
                v2f t1 = __builtin_elementwise_fma(rxp[p], (v2f){v.z, v.z},
                            __builtin_elementwise_fma(ryp[p], (v2f){v.w, v.w}, h1));
                mm[p] = __builtin_elementwise_max(mm[p],
                            __builtin_elementwise_max(t0, t1));
            }
        }
        float mmsc[4];
        #pragma unroll
        for (int p = 0; p < NPAIR; p++) {
            mmsc[2 * p] = mm[p].x; mmsc[2 * p + 1] = mm[p].y;
        }
        #pragma unroll
        for (int r = 0; r < 4; r++) {
            mmsc[r] = wred_max(mmsc[r]);
            mmsc[r] = __shfl(mmsc[r], 63);
        }
        v2f mmb[NPAIR];
        #pragma unroll
        for (int p = 0; p < NPAIR; p++) {
            mmb[p] = (v2f){mmsc[2 * p], mmsc[2 * p + 1]};
            sp[p] = (v2f){0.0f, 0.0f};
        }
        #pragma unroll 4
        for (int it = 0; it < NPTS / 128; it++) {
            float4 v = xy4[(it << 6) + lane];
            float2 h = hc2[(it << 6) + lane];
            #pragma unroll
            for (int p = 0; p < NPAIR; p++) {
                v2f h0 = (v2f){h.x, h.x} + nmest[p] - mmb[p];
                v2f h1 = (v2f){h.y, h.y} + nmest[p] - mmb[p];
                v2f t0 = __builtin_elementwise_fma(rxp[p], (v2f){v.x, v.x},
                            __builtin_elementwise_fma(ryp[p], (v2f){v.y, v.y}, h0));
                v2f t1 = __builtin_elementwise_fma(rxp[p], (v2f){v.z, v.z},
                            __builtin_elementwise_fma(ryp[p], (v2f){v.w, v.w}, h1));
                sp[p] += (v2f){FAST_EXP2(t0.x), FAST_EXP2(t0.y)};
                sp[p] += (v2f){FAST_EXP2(t1.x), FAST_EXP2(t1.y)};
            }
        }
        #pragma unroll
        for (int p = 0; p < NPAIR; p++) {
            s[2 * p]     = wred_sum(sp[p].x);
            s[2 * p + 1] = wred_sum(sp[p].y);
            mesc[2 * p] += mmb[p].x;
            mesc[2 * p + 1] += mmb[p].y;
        }
        __builtin_amdgcn_s_setprio(0);
    }

    if (lane == 63) {
        float4 qout, Lout, Hout;
        float part = 0.0f;
        if (initPhase) {
            bse4.x = FAST_LOG2(wrow[gidx0]);
            bse4.y = FAST_LOG2(wrow[gidx0 + 1]);
            bse4.z = FAST_LOG2(wrow[gidx0 + 2]);
            bse4.w = FAST_LOG2(wrow[gidx0 + 3]);
        }
        const float* qpv = (const float*)&qprev4;
        const float* bs = (const float*)&bse4;
        float* qo = (float*)&qout;
        float* Lo = (float*)&Lout;
        float* Ho = (float*)&Hout;
        #pragma unroll
        for (int r = 0; r < 4; r++) {
            float L = mesc[r] + FAST_LOG2(s[r]);
            float sm = -eps * LN2 * fmaf(n2o[r], sc, L);  // -eps*ln2*(hr + L)
            float fprev = qpv[r] - n2o[r];
            float fnew = c_old * fprev + c_new * sm;
            qo[r] = fnew + n2o[r];
            Lo[r] = L;
            Ho[r] = fmaf(qo[r], scNext, bs[r]);
            if (finalPhase) part += wrow[gidx0 + r] * fnew;
        }
        if (!finalPhase) {
            *(float4*)&qW[side * NE + gidx0] = qout;
            *(float4*)&Ls[side * NE + gidx0] = Lout;
            *(float4*)&HW[side * NE + gidx0] = Hout;
        } else {
            pw[wv] = part;
        }
    }
    if (finalPhase) {
        __syncthreads();
        if (threadIdx.x == 0) {
            float t = 0.0f;
            #pragma unroll
            for (int i = 0; i < 8; i++) t += pw[i];
            partials[hw] = t;
        }
    }
}

__global__ __launch_bounds__(512) void final_reduce(
    const float* __restrict__ partials, float* __restrict__ out)
{
    float v = partials[threadIdx.x] + partials[threadIdx.x + 512];
    v += __shfl_xor(v, 32);
    v += __shfl_xor(v, 16);
    v += __shfl_xor(v, 8);
    v += __shfl_xor(v, 4);
    v += __shfl_xor(v, 2);
    v += __shfl_xor(v, 1);
    __shared__ float ws8[8];
    if ((threadIdx.x & 63) == 0) ws8[threadIdx.x >> 6] = v;
    __syncthreads();
    if (threadIdx.x == 0) {
        float t = 0.0f;
        #pragma unroll
        for (int i = 0; i < 8; i++) t += ws8[i];
        out[0] = t * (1.0f / NB);
    }
}

extern "C" void kernel_launch(void* const* d_in, const int* in_sizes, int n_in,
                              void* d_out, int out_size, void* d_ws, size_t ws_size,
                              hipStream_t stream)
{
    const float* a = (const float*)d_in[0];
    const float* x = (const float*)d_in[1];
    const float* b = (const float*)d_in[2];
    const float* y = (const float*)d_in[3];
    float* out = (float*)d_out;

    float* ws = (float*)d_ws;
    float* q0 = ws;                 // [2][NB][NPTS]  (q = pot + n2)
    float* q1 = ws + 2 * NE;
    float* H0 = ws + 4 * NE;        // [2][NB][NPTS]  (H = fma(q, sc, bse))
    float* H1 = ws + 6 * NE;
    float* Ls = ws + 8 * NE;        // [2][NB][NPTS]
    float* colBase = ws + 10 * NE;  // [2][NB][NPTS]
    float* partials = ws + 12 * NE; // 1024 floats

    // eps annealing schedule (host-side, as in reference)
    double eps_list[32];
    int ne = 0;
    const double eps_final = 0.05 * 0.05;   // blur^p
    double eps = 2.0 * 2.0;                  // diameter^p
    while (eps > eps_final) { eps_list[ne++] = eps; eps *= 0.64; }  // scaling^p
    eps_list[ne++] = eps_final;              // ne == 18

    const float LOG2E_H = 1.4426950408889634f;
    const float* qp = q0; float* qn = q1;
    const float* Hp = H0; float* Hn = H1;

    auto phase = [&](double e, double e_prev, double e_next,
                     float c_old, float c_new, int init, int fin) {
        sinkhorn_phase<<<1024, THREADS, 0, stream>>>(
            x, y, a, b, qp, qn, Hp, Hn, Ls, colBase, partials,
            (float)e, (float)(1.0 / e), c_old, c_new,
            (float)((1.0 / e_next) * LOG2E_H),
            (float)(e_prev / e), init, fin);
    };
    auto swapbuf = [&]() {
        const float* t = qp; qp = qn; qn = (float*)t;
        const float* h = Hp; Hp = Hn; Hn = (float*)h;
    };

    // init at eps0 (mest=0 in-band; band check still guards correctness)
    phase(eps_list[0], eps_list[0], eps_list[0], 0.0f, 1.0f, 1, 0);
    swapbuf();
    // annealed damped iterations
    double e_prev = eps_list[0];
    for (int k = 0; k < ne; k++) {
        double e_next = (k + 1 < ne) ? eps_list[k + 1] : eps_list[ne - 1];
        phase(eps_list[k], e_prev, e_next, 0.5f, 0.5f, 0, 0);
        e_prev = eps_list[k];
        swapbuf();
    }
    // final extrapolation at eps_final (no damping) + fused partial loss
    phase(eps_list[ne - 1], e_prev, eps_list[ne - 1], 0.0f, 1.0f, 0, 1);

    final_reduce<<<1, 512, 0, stream>>>(partials, out);
}